// Round 1
// baseline (4669.980 us; speedup 1.0000x reference)
//
#include <hip/hip_runtime.h>
#include <math.h>

#define BB 2
#define LL 1024
#define DM 768
#define NL 2
#define VV 50264
#define DS 16
#define DI 1536
#define DR 48
#define DC 4
#define MM (BB*LL)

#define TS 64
#define KT 16

// ---------------- embedding gather ----------------
__global__ __launch_bounds__(256) void embed_kernel(
    const int* __restrict__ ids, const float* __restrict__ emb, float* __restrict__ x)
{
    int m = blockIdx.x;
    int v = ids[m];
    const float* src = emb + (size_t)v * DM;
    float* dst = x + (size_t)m * DM;
    for (int i = threadIdx.x; i < DM; i += 256) dst[i] = src[i];
}

// ---------------- generic tiled GEMM ----------------
// C[M,N] = A[M,K] (row stride lda) * B (+bias) (+resid) (+act)
// TRANSB=false: B is [K,N] row-major.  TRANSB=true: B is [N,K] row-major (C=A*B^T).
// ACT: 0 = none, 1 = softplus
template<bool TRANSB, int ACT>
__global__ __launch_bounds__(256) void gemm_tiled(
    const float* __restrict__ A, const float* __restrict__ Bm,
    const float* __restrict__ bias, const float* __restrict__ resid,
    float* __restrict__ C, int M, int N, int K, int lda)
{
    __shared__ float As[KT][TS + 4];
    __shared__ float Bs[KT][TS + 4];
    int tid = threadIdx.x;
    int tx = tid & 15, ty = tid >> 4;
    int m0 = blockIdx.y * TS;
    int n0 = blockIdx.x * TS;
    float acc[4][4] = {};

    for (int k0 = 0; k0 < K; k0 += KT) {
        // A tile: 64 (m) x 16 (k); each thread one float4 along k
        {
            int i = tid >> 2;
            int k4 = (tid & 3) * 4;
            int m = m0 + i;
            float4 v = make_float4(0.f, 0.f, 0.f, 0.f);
            if (m < M) v = *(const float4*)(A + (size_t)m * lda + k0 + k4);
            As[k4 + 0][i] = v.x; As[k4 + 1][i] = v.y;
            As[k4 + 2][i] = v.z; As[k4 + 3][i] = v.w;
        }
        if (!TRANSB) {
            // B tile: 16 (k) x 64 (n)
            int k = tid >> 4;
            int j4 = (tid & 15) * 4;
            int n = n0 + j4;
            float4 v = make_float4(0.f, 0.f, 0.f, 0.f);
            const float* p = Bm + (size_t)(k0 + k) * N + n;
            if (n + 3 < N) {
                v = *(const float4*)p;
            } else {
                float t0 = (n + 0 < N) ? p[0] : 0.f;
                float t1 = (n + 1 < N) ? p[1] : 0.f;
                float t2 = (n + 2 < N) ? p[2] : 0.f;
                float t3 = (n + 3 < N) ? p[3] : 0.f;
                v = make_float4(t0, t1, t2, t3);
            }
            Bs[k][j4 + 0] = v.x; Bs[k][j4 + 1] = v.y;
            Bs[k][j4 + 2] = v.z; Bs[k][j4 + 3] = v.w;
        } else {
            // B tile from [N,K]: 64 (n) x 16 (k)
            int j = tid >> 2;
            int k4 = (tid & 3) * 4;
            int n = n0 + j;
            float4 v = make_float4(0.f, 0.f, 0.f, 0.f);
            if (n < N) v = *(const float4*)(Bm + (size_t)n * K + k0 + k4);
            Bs[k4 + 0][j] = v.x; Bs[k4 + 1][j] = v.y;
            Bs[k4 + 2][j] = v.z; Bs[k4 + 3][j] = v.w;
        }
        __syncthreads();
        #pragma unroll
        for (int k = 0; k < KT; ++k) {
            float a[4], b[4];
            #pragma unroll
            for (int q = 0; q < 4; ++q) a[q] = As[k][ty * 4 + q];
            #pragma unroll
            for (int q = 0; q < 4; ++q) b[q] = Bs[k][tx * 4 + q];
            #pragma unroll
            for (int i = 0; i < 4; ++i)
                #pragma unroll
                for (int j = 0; j < 4; ++j)
                    acc[i][j] = fmaf(a[i], b[j], acc[i][j]);
        }
        __syncthreads();
    }

    #pragma unroll
    for (int i = 0; i < 4; ++i) {
        int m = m0 + ty * 4 + i;
        if (m >= M) continue;
        #pragma unroll
        for (int j = 0; j < 4; ++j) {
            int n = n0 + tx * 4 + j;
            if (n >= N) continue;
            float v = acc[i][j];
            if (bias)  v += bias[n];
            if (resid) v += resid[(size_t)m * N + n];
            if (ACT == 1) v = fmaxf(v, 0.f) + log1pf(expf(-fabsf(v)));
            C[(size_t)m * N + n] = v;
        }
    }
}

// ---------------- causal depthwise conv1d + SiLU ----------------
__global__ __launch_bounds__(256) void conv_silu_kernel(
    const float* __restrict__ xr, const float* __restrict__ cw,
    const float* __restrict__ cb, float* __restrict__ u)
{
    int d = blockIdx.x * 256 + threadIdx.x;   // 0..DI-1
    int l = blockIdx.y;
    int b = blockIdx.z;
    float acc = cb[d];
    #pragma unroll
    for (int j = 0; j < DC; ++j) {
        int lp = l - (DC - 1) + j;
        if (lp >= 0)
            acc = fmaf(xr[((size_t)(b * LL + lp)) * (2 * DI) + d], cw[d * DC + j], acc);
    }
    // silu
    float s = acc / (1.f + expf(-acc));
    u[((size_t)(b * LL + l)) * DI + d] = s;
}

// ---------------- fused ZOH + selective scan ----------------
// thread layout: 256 = 16 d x 16 n; grid (DI/16, B)
__global__ __launch_bounds__(256) void scan_kernel(
    const float* __restrict__ delta, const float* __restrict__ u,
    const float* __restrict__ dbc, const float* __restrict__ xr,
    const float* __restrict__ A_log, const float* __restrict__ Dp,
    float* __restrict__ y)
{
    int tid = threadIdx.x;
    int n = tid & 15;
    int d = blockIdx.x * 16 + (tid >> 4);
    int b = blockIdx.y;

    float Av = -expf(A_log[(size_t)d * DS + n]);
    float Dv = Dp[d];
    float inv_Aeps = 1.f / (Av + 1e-7f);
    float s = 0.f;

    const float* dp = delta + (size_t)b * LL * DI + d;
    const float* up = u     + (size_t)b * LL * DI + d;
    const float* xp = xr    + (size_t)b * LL * (2 * DI) + DI + d;
    const float* bp = dbc   + (size_t)b * LL * 80 + DR + n;        // B: cols 48..63
    const float* cp = dbc   + (size_t)b * LL * 80 + DR + DS + n;   // C: cols 64..79
    float* yp = y + (size_t)b * LL * DI + d;

    for (int l = 0; l < LL; ++l) {
        float dlt = dp[(size_t)l * DI];
        float uv  = up[(size_t)l * DI];
        float Bv  = bp[(size_t)l * 80];
        float Cv  = cp[(size_t)l * 80];
        float dA  = expf(dlt * Av);
        float dBu = (dA - 1.f) * inv_Aeps * Bv * uv;
        s = fmaf(dA, s, dBu);
        float pv = s * Cv;
        pv += __shfl_xor(pv, 1);
        pv += __shfl_xor(pv, 2);
        pv += __shfl_xor(pv, 4);
        pv += __shfl_xor(pv, 8);
        if (n == 0) {
            float rv = xp[(size_t)l * (2 * DI)];
            float res = rv / (1.f + expf(-rv));
            yp[(size_t)l * DI] = (pv + uv * Dv) * res;
        }
    }
}

// ---------------- RMSNorm ----------------
__global__ __launch_bounds__(256) void rmsnorm_kernel(
    const float* __restrict__ in, const float* __restrict__ w, float* __restrict__ out)
{
    int m = blockIdx.x;
    const float* row = in + (size_t)m * DM;
    float ss = 0.f;
    for (int i = threadIdx.x; i < DM; i += 256) { float v = row[i]; ss = fmaf(v, v, ss); }
    #pragma unroll
    for (int off = 32; off > 0; off >>= 1) ss += __shfl_down(ss, off);
    __shared__ float sred[4];
    __shared__ float sscale;
    int wid = threadIdx.x >> 6;
    if ((threadIdx.x & 63) == 0) sred[wid] = ss;
    __syncthreads();
    if (threadIdx.x == 0) {
        float tot = sred[0] + sred[1] + sred[2] + sred[3];
        sscale = 1.f / sqrtf(tot / (float)DM + 1e-5f);
    }
    __syncthreads();
    float sc = sscale;
    for (int i = threadIdx.x; i < DM; i += 256)
        out[(size_t)m * DM + i] = row[i] * sc * w[i];
}

// ---------------- launch ----------------
extern "C" void kernel_launch(void* const* d_in, const int* in_sizes, int n_in,
                              void* d_out, int out_size, void* d_ws, size_t ws_size,
                              hipStream_t stream)
{
    const int*   ids      = (const int*)  d_in[0];
    const float* emb      = (const float*)d_in[1];
    const float* in_w     = (const float*)d_in[2];
    const float* in_b     = (const float*)d_in[3];
    const float* conv_w   = (const float*)d_in[4];
    const float* conv_b   = (const float*)d_in[5];
    const float* xproj_w  = (const float*)d_in[6];
    const float* dt_w     = (const float*)d_in[7];
    const float* dt_b     = (const float*)d_in[8];
    const float* A_log    = (const float*)d_in[9];
    const float* Dp       = (const float*)d_in[10];
    const float* out_w    = (const float*)d_in[11];
    const float* out_b    = (const float*)d_in[12];
    const float* norm_w   = (const float*)d_in[13];
    const float* normf_w  = (const float*)d_in[14];
    float* out = (float*)d_out;

    float* ws = (float*)d_ws;
    float* x     = ws;                               // M*DM
    float* xr    = x     + (size_t)MM * DM;          // M*2DI
    float* u     = xr    + (size_t)MM * 2 * DI;      // M*DI
    float* dbc   = u     + (size_t)MM * DI;          // M*80
    float* delta = dbc   + (size_t)MM * 80;          // M*DI
    float* yb    = delta + (size_t)MM * DI;          // M*DI
    float* tmp   = yb    + (size_t)MM * DI;          // M*DM

    embed_kernel<<<MM, 256, 0, stream>>>(ids, emb, x);

    for (int layer = 0; layer < NL; ++layer) {
        const float* lw_in  = in_w    + (size_t)layer * DM * 2 * DI;
        const float* lb_in  = in_b    + (size_t)layer * 2 * DI;
        const float* lcw    = conv_w  + (size_t)layer * DI * DC;
        const float* lcb    = conv_b  + (size_t)layer * DI;
        const float* lxw    = xproj_w + (size_t)layer * DI * (DR + 2 * DS);
        const float* ldtw   = dt_w    + (size_t)layer * DR * DI;
        const float* ldtb   = dt_b    + (size_t)layer * DI;
        const float* lAlog  = A_log   + (size_t)layer * DI * DS;
        const float* lDp    = Dp      + (size_t)layer * DI;
        const float* low    = out_w   + (size_t)layer * DI * DM;
        const float* lob    = out_b   + (size_t)layer * DM;
        const float* lnw    = norm_w  + (size_t)layer * DM;

        // xr = x @ in_w + in_b           (M x 2DI, K=DM)
        gemm_tiled<false, 0><<<dim3(2 * DI / TS, MM / TS), 256, 0, stream>>>(
            x, lw_in, lb_in, nullptr, xr, MM, 2 * DI, DM, DM);

        // u = silu(causal_conv(xr[:, :DI]) + conv_b)
        conv_silu_kernel<<<dim3(DI / 256, LL, BB), 256, 0, stream>>>(xr, lcw, lcb, u);

        // dbc = u @ xproj_w              (M x 80, K=DI)
        gemm_tiled<false, 0><<<dim3((80 + TS - 1) / TS, MM / TS), 256, 0, stream>>>(
            u, lxw, nullptr, nullptr, dbc, MM, DR + 2 * DS, DI, DI);

        // delta = softplus(dbc[:, :48] @ dt_w + dt_b)   (M x DI, K=48, lda=80)
        gemm_tiled<false, 1><<<dim3(DI / TS, MM / TS), 256, 0, stream>>>(
            dbc, ldtw, ldtb, nullptr, delta, MM, DI, DR, DR + 2 * DS);

        // y = scan(...) * silu(res)
        scan_kernel<<<dim3(DI / 16, BB), 256, 0, stream>>>(
            delta, u, dbc, xr, lAlog, lDp, yb);

        // tmp = y @ out_w + out_b + x    (M x DM, K=DI)
        gemm_tiled<false, 0><<<dim3(DM / TS, MM / TS), 256, 0, stream>>>(
            yb, low, lob, x, tmp, MM, DM, DI, DI);

        // x = rmsnorm(tmp, norm_w)
        rmsnorm_kernel<<<MM, 256, 0, stream>>>(tmp, lnw, x);
    }

    // xf = rmsnorm(x, normf_w)
    rmsnorm_kernel<<<MM, 256, 0, stream>>>(x, normf_w, tmp);

    // logits = xf @ emb^T    (M x V, K=DM)
    gemm_tiled<true, 0><<<dim3((VV + TS - 1) / TS, MM / TS), 256, 0, stream>>>(
        tmp, emb, nullptr, nullptr, out, MM, VV, DM, DM);
}

// Round 2
// 2492.099 us; speedup vs baseline: 1.8739x; 1.8739x over previous
//
#include <hip/hip_runtime.h>
#include <math.h>
#include <stdint.h>

#define BB 2
#define LL 1024
#define DM 768
#define NL 2
#define VV 50264
#define VPAD 50304   // 393 * 128
#define DS 16
#define DI 1536
#define DR 48
#define DC 4
#define MM (BB*LL)

#define TS 64
#define KT 16

typedef __attribute__((ext_vector_type(8))) short short8;
typedef __attribute__((ext_vector_type(4))) float f32x4;

#define AS3(p) ((__attribute__((address_space(3))) unsigned int*)(unsigned int)(uintptr_t)(p))
#define AS1(p) ((const __attribute__((address_space(1))) unsigned int*)(uintptr_t)(p))

__device__ __forceinline__ unsigned short f2bf(float v) {
    union { float f; unsigned u; } x; x.f = v;
    unsigned r = x.u + 0x7fffu + ((x.u >> 16) & 1u);
    return (unsigned short)(r >> 16);
}

// ---------------- embedding gather ----------------
__global__ __launch_bounds__(256) void embed_kernel(
    const int* __restrict__ ids, const float* __restrict__ emb, float* __restrict__ x)
{
    int m = blockIdx.x;
    int v = ids[m];
    const float* src = emb + (size_t)v * DM;
    float* dst = x + (size_t)m * DM;
    for (int i = threadIdx.x; i < DM; i += 256) dst[i] = src[i];
}

// ---------------- f32 -> bf16 convert (n4 = n/4) ----------------
__global__ __launch_bounds__(256) void f32_to_bf16_kernel(
    const float* __restrict__ in, unsigned short* __restrict__ out, int n4)
{
    int i = blockIdx.x * 256 + threadIdx.x;
    if (i < n4) {
        float4 v = ((const float4*)in)[i];
        ushort4 o;
        o.x = f2bf(v.x); o.y = f2bf(v.y); o.z = f2bf(v.z); o.w = f2bf(v.w);
        ((ushort4*)out)[i] = o;
    }
}

// ---------------- emb f32 [VV][DM] -> bf16 [VPAD][DM] (pad rows = 0) ----------------
__global__ __launch_bounds__(256) void emb_convert_kernel(
    const float* __restrict__ emb, unsigned short* __restrict__ out)
{
    int row = blockIdx.x;
    unsigned short* op = out + (size_t)row * DM;
    if (row < VV) {
        const float* ip = emb + (size_t)row * DM;
        for (int i = threadIdx.x; i < DM; i += 256) op[i] = f2bf(ip[i]);
    } else {
        for (int i = threadIdx.x; i < DM; i += 256) op[i] = 0;
    }
}

// ---------------- transpose+convert: in [L][R][C] f32 -> out [L][C][R] bf16 ----------------
__global__ __launch_bounds__(256) void transpose_bf16_kernel(
    const float* __restrict__ in, unsigned short* __restrict__ out, int R, int C)
{
    __shared__ float t[32][33];
    int l = blockIdx.z;
    int r0 = blockIdx.y * 32, c0 = blockIdx.x * 32;
    int tx = threadIdx.x & 31, ty = threadIdx.x >> 5;   // 32 x 8
    const float* ip = in + (size_t)l * R * C;
    unsigned short* op = out + (size_t)l * C * R;
    #pragma unroll
    for (int j = 0; j < 32; j += 8)
        t[ty + j][tx] = ip[(size_t)(r0 + ty + j) * C + c0 + tx];
    __syncthreads();
    #pragma unroll
    for (int j = 0; j < 32; j += 8)
        op[(size_t)(c0 + ty + j) * R + r0 + tx] = f2bf(t[tx][ty + j]);
}

// ---------------- MFMA bf16 GEMM: C = A[M,K] * B[Npad,K]^T (+bias) (+resid) ----------------
// 128x128 tile, BK=32, 4 waves (2x2), each wave 64x64 via 4x4 frags of 16x16x32.
// N = real column count for writes/bias/resid (row stride of C); tiles are padded.
__global__ __launch_bounds__(256) void gemm_mfma_bt(
    const unsigned short* __restrict__ A, const unsigned short* __restrict__ B,
    const float* __restrict__ bias, const float* __restrict__ resid,
    float* __restrict__ C, int M, int N, int K)
{
    __shared__ unsigned short As[128 * 32];
    __shared__ unsigned short Bs[128 * 32];
    int tid = threadIdx.x;
    int w = tid >> 6, lane = tid & 63;
    int m0 = blockIdx.y * 128, n0 = blockIdx.x * 128;

    // staging addresses: wave w stages rows [w*16, w*16+16) and [64+w*16, ...)
    int rA = lane >> 2;            // row within 16-row group
    int kb = (lane & 3) * 8;       // bf16 offset within row (16B granules)
    const unsigned short* gA0 = A + (size_t)(m0 + w * 16 + rA) * K + kb;
    const unsigned short* gA1 = gA0 + (size_t)64 * K;
    const unsigned short* gB0 = B + (size_t)(n0 + w * 16 + rA) * K + kb;
    const unsigned short* gB1 = gB0 + (size_t)64 * K;
    unsigned short* lA0 = &As[(w * 16) * 32];
    unsigned short* lA1 = &As[(64 + w * 16) * 32];
    unsigned short* lB0 = &Bs[(w * 16) * 32];
    unsigned short* lB1 = &Bs[(64 + w * 16) * 32];

    int lr = lane & 15, lk = lane >> 4;
    int wr = (w >> 1) * 64, wc = (w & 1) * 64;

    f32x4 acc[4][4] = {};

    for (int k0 = 0; k0 < K; k0 += 32) {
        __builtin_amdgcn_global_load_lds(AS1(gA0 + k0), AS3(lA0), 16, 0, 0);
        __builtin_amdgcn_global_load_lds(AS1(gA1 + k0), AS3(lA1), 16, 0, 0);
        __builtin_amdgcn_global_load_lds(AS1(gB0 + k0), AS3(lB0), 16, 0, 0);
        __builtin_amdgcn_global_load_lds(AS1(gB1 + k0), AS3(lB1), 16, 0, 0);
        __syncthreads();

        short8 a[4], b[4];
        #pragma unroll
        for (int f = 0; f < 4; ++f)
            a[f] = *(const short8*)&As[(wr + f * 16 + lr) * 32 + lk * 8];
        #pragma unroll
        for (int f = 0; f < 4; ++f)
            b[f] = *(const short8*)&Bs[(wc + f * 16 + lr) * 32 + lk * 8];
        #pragma unroll
        for (int i = 0; i < 4; ++i)
            #pragma unroll
            for (int j = 0; j < 4; ++j)
                acc[i][j] = __builtin_amdgcn_mfma_f32_16x16x32_bf16(a[i], b[j], acc[i][j], 0, 0, 0);
        __syncthreads();
    }

    #pragma unroll
    for (int i = 0; i < 4; ++i) {
        int row = m0 + wr + i * 16 + lk * 4;
        #pragma unroll
        for (int j = 0; j < 4; ++j) {
            int col = n0 + wc + j * 16 + lr;
            if (col < N) {
                float bv = bias ? bias[col] : 0.f;
                #pragma unroll
                for (int r = 0; r < 4; ++r) {
                    float v = acc[i][j][r] + bv;
                    if (resid) v += resid[(size_t)(row + r) * N + col];
                    C[(size_t)(row + r) * N + col] = v;
                }
            }
        }
    }
}

// ---------------- f32 tiled GEMM (small shapes: xproj, dt) ----------------
// ACT: 0 = none, 1 = softplus
template<int ACT>
__global__ __launch_bounds__(256) void gemm_tiled(
    const float* __restrict__ A, const float* __restrict__ Bm,
    const float* __restrict__ bias, float* __restrict__ C,
    int M, int N, int K, int lda)
{
    __shared__ float As[KT][TS + 4];
    __shared__ float Bs[KT][TS + 4];
    int tid = threadIdx.x;
    int tx = tid & 15, ty = tid >> 4;
    int m0 = blockIdx.y * TS;
    int n0 = blockIdx.x * TS;
    float acc[4][4] = {};

    for (int k0 = 0; k0 < K; k0 += KT) {
        {
            int i = tid >> 2;
            int k4 = (tid & 3) * 4;
            int m = m0 + i;
            float4 v = make_float4(0.f, 0.f, 0.f, 0.f);
            if (m < M) v = *(const float4*)(A + (size_t)m * lda + k0 + k4);
            As[k4 + 0][i] = v.x; As[k4 + 1][i] = v.y;
            As[k4 + 2][i] = v.z; As[k4 + 3][i] = v.w;
        }
        {
            int k = tid >> 4;
            int j4 = (tid & 15) * 4;
            int n = n0 + j4;
            float4 v = make_float4(0.f, 0.f, 0.f, 0.f);
            const float* p = Bm + (size_t)(k0 + k) * N + n;
            if (n + 3 < N) {
                v = *(const float4*)p;
            } else {
                float t0 = (n + 0 < N) ? p[0] : 0.f;
                float t1 = (n + 1 < N) ? p[1] : 0.f;
                float t2 = (n + 2 < N) ? p[2] : 0.f;
                float t3 = (n + 3 < N) ? p[3] : 0.f;
                v = make_float4(t0, t1, t2, t3);
            }
            Bs[k][j4 + 0] = v.x; Bs[k][j4 + 1] = v.y;
            Bs[k][j4 + 2] = v.z; Bs[k][j4 + 3] = v.w;
        }
        __syncthreads();
        #pragma unroll
        for (int k = 0; k < KT; ++k) {
            float a[4], b[4];
            #pragma unroll
            for (int q = 0; q < 4; ++q) a[q] = As[k][ty * 4 + q];
            #pragma unroll
            for (int q = 0; q < 4; ++q) b[q] = Bs[k][tx * 4 + q];
            #pragma unroll
            for (int i = 0; i < 4; ++i)
                #pragma unroll
                for (int j = 0; j < 4; ++j)
                    acc[i][j] = fmaf(a[i], b[j], acc[i][j]);
        }
        __syncthreads();
    }

    #pragma unroll
    for (int i = 0; i < 4; ++i) {
        int m = m0 + ty * 4 + i;
        if (m >= M) continue;
        #pragma unroll
        for (int j = 0; j < 4; ++j) {
            int n = n0 + tx * 4 + j;
            if (n >= N) continue;
            float v = acc[i][j];
            if (bias)  v += bias[n];
            if (ACT == 1) v = fmaxf(v, 0.f) + log1pf(expf(-fabsf(v)));
            C[(size_t)m * N + n] = v;
        }
    }
}

// ---------------- causal depthwise conv1d + SiLU ----------------
__global__ __launch_bounds__(256) void conv_silu_kernel(
    const float* __restrict__ xr, const float* __restrict__ cw,
    const float* __restrict__ cb, float* __restrict__ u)
{
    int d = blockIdx.x * 256 + threadIdx.x;
    int l = blockIdx.y;
    int b = blockIdx.z;
    float acc = cb[d];
    #pragma unroll
    for (int j = 0; j < DC; ++j) {
        int lp = l - (DC - 1) + j;
        if (lp >= 0)
            acc = fmaf(xr[((size_t)(b * LL + lp)) * (2 * DI) + d], cw[d * DC + j], acc);
    }
    float s = acc / (1.f + expf(-acc));
    u[((size_t)(b * LL + l)) * DI + d] = s;
}

// ---------------- fused ZOH + selective scan ----------------
__global__ __launch_bounds__(256) void scan_kernel(
    const float* __restrict__ delta, const float* __restrict__ u,
    const float* __restrict__ dbc, const float* __restrict__ xr,
    const float* __restrict__ A_log, const float* __restrict__ Dp,
    float* __restrict__ y)
{
    int tid = threadIdx.x;
    int n = tid & 15;
    int d = blockIdx.x * 16 + (tid >> 4);
    int b = blockIdx.y;

    float Av = -expf(A_log[(size_t)d * DS + n]);
    float Dv = Dp[d];
    float inv_Aeps = 1.f / (Av + 1e-7f);
    float s = 0.f;

    const float* dp = delta + (size_t)b * LL * DI + d;
    const float* up = u     + (size_t)b * LL * DI + d;
    const float* xp = xr    + (size_t)b * LL * (2 * DI) + DI + d;
    const float* bp = dbc   + (size_t)b * LL * 80 + DR + n;
    const float* cp = dbc   + (size_t)b * LL * 80 + DR + DS + n;
    float* yp = y + (size_t)b * LL * DI + d;

    for (int l = 0; l < LL; ++l) {
        float dlt = dp[(size_t)l * DI];
        float uv  = up[(size_t)l * DI];
        float Bv  = bp[(size_t)l * 80];
        float Cv  = cp[(size_t)l * 80];
        float dA  = expf(dlt * Av);
        float dBu = (dA - 1.f) * inv_Aeps * Bv * uv;
        s = fmaf(dA, s, dBu);
        float pv = s * Cv;
        pv += __shfl_xor(pv, 1);
        pv += __shfl_xor(pv, 2);
        pv += __shfl_xor(pv, 4);
        pv += __shfl_xor(pv, 8);
        if (n == 0) {
            float rv = xp[(size_t)l * (2 * DI)];
            float res = rv / (1.f + expf(-rv));
            yp[(size_t)l * DI] = (pv + uv * Dv) * res;
        }
    }
}

// ---------------- RMSNorm ----------------
__global__ __launch_bounds__(256) void rmsnorm_kernel(
    const float* __restrict__ in, const float* __restrict__ w, float* __restrict__ out)
{
    int m = blockIdx.x;
    const float* row = in + (size_t)m * DM;
    float ss = 0.f;
    for (int i = threadIdx.x; i < DM; i += 256) { float v = row[i]; ss = fmaf(v, v, ss); }
    #pragma unroll
    for (int off = 32; off > 0; off >>= 1) ss += __shfl_down(ss, off);
    __shared__ float sred[4];
    __shared__ float sscale;
    int wid = threadIdx.x >> 6;
    if ((threadIdx.x & 63) == 0) sred[wid] = ss;
    __syncthreads();
    if (threadIdx.x == 0) {
        float tot = sred[0] + sred[1] + sred[2] + sred[3];
        sscale = 1.f / sqrtf(tot / (float)DM + 1e-5f);
    }
    __syncthreads();
    float sc = sscale;
    for (int i = threadIdx.x; i < DM; i += 256)
        out[(size_t)m * DM + i] = row[i] * sc * w[i];
}

// ---------------- launch ----------------
extern "C" void kernel_launch(void* const* d_in, const int* in_sizes, int n_in,
                              void* d_out, int out_size, void* d_ws, size_t ws_size,
                              hipStream_t stream)
{
    const int*   ids      = (const int*)  d_in[0];
    const float* emb      = (const float*)d_in[1];
    const float* in_w     = (const float*)d_in[2];
    const float* in_b     = (const float*)d_in[3];
    const float* conv_w   = (const float*)d_in[4];
    const float* conv_b   = (const float*)d_in[5];
    const float* xproj_w  = (const float*)d_in[6];
    const float* dt_w     = (const float*)d_in[7];
    const float* dt_b     = (const float*)d_in[8];
    const float* A_log    = (const float*)d_in[9];
    const float* Dp       = (const float*)d_in[10];
    const float* out_w    = (const float*)d_in[11];
    const float* out_b    = (const float*)d_in[12];
    const float* norm_w   = (const float*)d_in[13];
    const float* normf_w  = (const float*)d_in[14];
    float* out = (float*)d_out;

    // workspace layout (256B aligned chunks)
    char* wsp = (char*)d_ws;
    auto alloc = [&](size_t bytes) {
        char* p = wsp;
        wsp += (bytes + 255) & ~(size_t)255;
        return p;
    };
    float* x     = (float*)alloc((size_t)MM * DM * 4);
    float* xr    = (float*)alloc((size_t)MM * 2 * DI * 4);
    float* u     = (float*)alloc((size_t)MM * DI * 4);
    float* dbc   = (float*)alloc((size_t)MM * 80 * 4);
    float* delta = (float*)alloc((size_t)MM * DI * 4);
    float* yb    = (float*)alloc((size_t)MM * DI * 4);
    float* tmp   = (float*)alloc((size_t)MM * DM * 4);
    unsigned short* a16     = (unsigned short*)alloc((size_t)MM * DI * 2);
    unsigned short* emb16   = (unsigned short*)alloc((size_t)VPAD * DM * 2);
    unsigned short* in_wT   = (unsigned short*)alloc((size_t)NL * 2 * DI * DM * 2);
    unsigned short* out_wT  = (unsigned short*)alloc((size_t)NL * DM * DI * 2);

    // ---- weight prep (runs every call; cheap vs. total) ----
    emb_convert_kernel<<<VPAD, 256, 0, stream>>>(emb, emb16);
    // in_w [NL][DM][2DI] -> in_wT [NL][2DI][DM]
    transpose_bf16_kernel<<<dim3(2 * DI / 32, DM / 32, NL), 256, 0, stream>>>(
        in_w, in_wT, DM, 2 * DI);
    // out_w [NL][DI][DM] -> out_wT [NL][DM][DI]
    transpose_bf16_kernel<<<dim3(DM / 32, DI / 32, NL), 256, 0, stream>>>(
        out_w, out_wT, DI, DM);

    embed_kernel<<<MM, 256, 0, stream>>>(ids, emb, x);

    for (int layer = 0; layer < NL; ++layer) {
        const float* lb_in  = in_b    + (size_t)layer * 2 * DI;
        const float* lcw    = conv_w  + (size_t)layer * DI * DC;
        const float* lcb    = conv_b  + (size_t)layer * DI;
        const float* lxw    = xproj_w + (size_t)layer * DI * (DR + 2 * DS);
        const float* ldtw   = dt_w    + (size_t)layer * DR * DI;
        const float* ldtb   = dt_b    + (size_t)layer * DI;
        const float* lAlog  = A_log   + (size_t)layer * DI * DS;
        const float* lDp    = Dp      + (size_t)layer * DI;
        const float* lob    = out_b   + (size_t)layer * DM;
        const float* lnw    = norm_w  + (size_t)layer * DM;
        const unsigned short* lw_inT = in_wT  + (size_t)layer * 2 * DI * DM;
        const unsigned short* lw_outT= out_wT + (size_t)layer * DM * DI;

        // x -> bf16
        f32_to_bf16_kernel<<<(MM * DM / 4 + 255) / 256, 256, 0, stream>>>(x, a16, MM * DM / 4);

        // xr = x @ in_w + in_b   (M=2048, N=3072, K=768)  [MFMA]
        gemm_mfma_bt<<<dim3(2 * DI / 128, MM / 128), 256, 0, stream>>>(
            a16, lw_inT, lb_in, nullptr, xr, MM, 2 * DI, DM);

        // u = silu(causal_conv(xr[:, :DI]) + conv_b)
        conv_silu_kernel<<<dim3(DI / 256, LL, BB), 256, 0, stream>>>(xr, lcw, lcb, u);

        // dbc = u @ xproj_w   (M x 80, K=DI) [f32]
        gemm_tiled<0><<<dim3((80 + TS - 1) / TS, MM / TS), 256, 0, stream>>>(
            u, lxw, nullptr, dbc, MM, DR + 2 * DS, DI, DI);

        // delta = softplus(dbc[:, :48] @ dt_w + dt_b)  (M x DI, K=48) [f32]
        gemm_tiled<1><<<dim3(DI / TS, MM / TS), 256, 0, stream>>>(
            dbc, ldtw, ldtb, delta, MM, DI, DR, DR + 2 * DS);

        // y = scan(...) * silu(res)
        scan_kernel<<<dim3(DI / 16, BB), 256, 0, stream>>>(
            delta, u, dbc, xr, lAlog, lDp, yb);

        // yb -> bf16
        f32_to_bf16_kernel<<<(MM * DI / 4 + 255) / 256, 256, 0, stream>>>(yb, a16, MM * DI / 4);

        // tmp = y @ out_w + out_b + x   (M x DM, K=DI)  [MFMA]
        gemm_mfma_bt<<<dim3(DM / 128, MM / 128), 256, 0, stream>>>(
            a16, lw_outT, lob, x, tmp, MM, DM, DI);

        // x = rmsnorm(tmp, norm_w)
        rmsnorm_kernel<<<MM, 256, 0, stream>>>(tmp, lnw, x);
    }

    // xf = rmsnorm(x, normf_w)
    rmsnorm_kernel<<<MM, 256, 0, stream>>>(x, normf_w, tmp);

    // xf -> bf16
    f32_to_bf16_kernel<<<(MM * DM / 4 + 255) / 256, 256, 0, stream>>>(tmp, a16, MM * DM / 4);

    // logits = xf @ emb^T   (M=2048, N=50264 (pad 50304), K=768)  [MFMA]
    gemm_mfma_bt<<<dim3(VPAD / 128, MM / 128), 256, 0, stream>>>(
        a16, emb16, nullptr, nullptr, out, MM, VV, DM);
}

// Round 3
// 1177.286 us; speedup vs baseline: 3.9667x; 2.1168x over previous
//
#include <hip/hip_runtime.h>
#include <math.h>
#include <stdint.h>

#define BB 2
#define LL 1024
#define DM 768
#define NL 2
#define VV 50264
#define VPAD 50304   // 393 * 128
#define DS 16
#define DI 1536
#define DR 48
#define DC 4
#define MM (BB*LL)

#define CH 64
#define NC (LL/CH)

#define TS 64
#define KT 16

typedef __attribute__((ext_vector_type(8))) short short8;
typedef __attribute__((ext_vector_type(4))) float f32x4;

#define AS3(p) ((__attribute__((address_space(3))) unsigned int*)(unsigned int)(uintptr_t)(p))
#define AS1(p) ((const __attribute__((address_space(1))) unsigned int*)(uintptr_t)(p))

__device__ __forceinline__ unsigned short f2bf(float v) {
    union { float f; unsigned u; } x; x.f = v;
    unsigned r = x.u + 0x7fffu + ((x.u >> 16) & 1u);
    return (unsigned short)(r >> 16);
}

// ---------------- embedding gather ----------------
__global__ __launch_bounds__(256) void embed_kernel(
    const int* __restrict__ ids, const float* __restrict__ emb, float* __restrict__ x)
{
    int m = blockIdx.x;
    int v = ids[m];
    const float* src = emb + (size_t)v * DM;
    float* dst = x + (size_t)m * DM;
    for (int i = threadIdx.x; i < DM; i += 256) dst[i] = src[i];
}

// ---------------- f32 -> bf16 convert (n4 = n/4) ----------------
__global__ __launch_bounds__(256) void f32_to_bf16_kernel(
    const float* __restrict__ in, unsigned short* __restrict__ out, int n4)
{
    int i = blockIdx.x * 256 + threadIdx.x;
    if (i < n4) {
        float4 v = ((const float4*)in)[i];
        ushort4 o;
        o.x = f2bf(v.x); o.y = f2bf(v.y); o.z = f2bf(v.z); o.w = f2bf(v.w);
        ((ushort4*)out)[i] = o;
    }
}

// ---------------- emb f32 [VV][DM] -> bf16 [VPAD][DM] (pad rows = 0) ----------------
__global__ __launch_bounds__(256) void emb_convert_kernel(
    const float* __restrict__ emb, unsigned short* __restrict__ out)
{
    int row = blockIdx.x;
    unsigned short* op = out + (size_t)row * DM;
    if (row < VV) {
        const float* ip = emb + (size_t)row * DM;
        for (int i = threadIdx.x; i < DM; i += 256) op[i] = f2bf(ip[i]);
    } else {
        for (int i = threadIdx.x; i < DM; i += 256) op[i] = 0;
    }
}

// ---------------- transpose+convert: in [L][R][C] f32 -> out [L][C][R] bf16 ----------------
__global__ __launch_bounds__(256) void transpose_bf16_kernel(
    const float* __restrict__ in, unsigned short* __restrict__ out, int R, int C)
{
    __shared__ float t[32][33];
    int l = blockIdx.z;
    int r0 = blockIdx.y * 32, c0 = blockIdx.x * 32;
    int tx = threadIdx.x & 31, ty = threadIdx.x >> 5;   // 32 x 8
    const float* ip = in + (size_t)l * R * C;
    unsigned short* op = out + (size_t)l * C * R;
    #pragma unroll
    for (int j = 0; j < 32; j += 8)
        t[ty + j][tx] = ip[(size_t)(r0 + ty + j) * C + c0 + tx];
    __syncthreads();
    #pragma unroll
    for (int j = 0; j < 32; j += 8)
        op[(size_t)(c0 + ty + j) * R + r0 + tx] = f2bf(t[tx][ty + j]);
}

// ---------------- MFMA bf16 GEMM: C = A[M,K] * B[Npad,K]^T (+bias) (+resid) ----------------
__global__ __launch_bounds__(256) void gemm_mfma_bt(
    const unsigned short* __restrict__ A, const unsigned short* __restrict__ B,
    const float* __restrict__ bias, const float* __restrict__ resid,
    float* __restrict__ C, int M, int N, int K)
{
    __shared__ unsigned short As[128 * 32];
    __shared__ unsigned short Bs[128 * 32];
    int tid = threadIdx.x;
    int w = tid >> 6, lane = tid & 63;
    int m0 = blockIdx.y * 128, n0 = blockIdx.x * 128;

    int rA = lane >> 2;
    int kb = (lane & 3) * 8;
    const unsigned short* gA0 = A + (size_t)(m0 + w * 16 + rA) * K + kb;
    const unsigned short* gA1 = gA0 + (size_t)64 * K;
    const unsigned short* gB0 = B + (size_t)(n0 + w * 16 + rA) * K + kb;
    const unsigned short* gB1 = gB0 + (size_t)64 * K;
    unsigned short* lA0 = &As[(w * 16) * 32];
    unsigned short* lA1 = &As[(64 + w * 16) * 32];
    unsigned short* lB0 = &Bs[(w * 16) * 32];
    unsigned short* lB1 = &Bs[(64 + w * 16) * 32];

    int lr = lane & 15, lk = lane >> 4;
    int wr = (w >> 1) * 64, wc = (w & 1) * 64;

    f32x4 acc[4][4] = {};

    for (int k0 = 0; k0 < K; k0 += 32) {
        __builtin_amdgcn_global_load_lds(AS1(gA0 + k0), AS3(lA0), 16, 0, 0);
        __builtin_amdgcn_global_load_lds(AS1(gA1 + k0), AS3(lA1), 16, 0, 0);
        __builtin_amdgcn_global_load_lds(AS1(gB0 + k0), AS3(lB0), 16, 0, 0);
        __builtin_amdgcn_global_load_lds(AS1(gB1 + k0), AS3(lB1), 16, 0, 0);
        __syncthreads();

        short8 a[4], b[4];
        #pragma unroll
        for (int f = 0; f < 4; ++f)
            a[f] = *(const short8*)&As[(wr + f * 16 + lr) * 32 + lk * 8];
        #pragma unroll
        for (int f = 0; f < 4; ++f)
            b[f] = *(const short8*)&Bs[(wc + f * 16 + lr) * 32 + lk * 8];
        #pragma unroll
        for (int i = 0; i < 4; ++i)
            #pragma unroll
            for (int j = 0; j < 4; ++j)
                acc[i][j] = __builtin_amdgcn_mfma_f32_16x16x32_bf16(a[i], b[j], acc[i][j], 0, 0, 0);
        __syncthreads();
    }

    #pragma unroll
    for (int i = 0; i < 4; ++i) {
        int row = m0 + wr + i * 16 + lk * 4;
        #pragma unroll
        for (int j = 0; j < 4; ++j) {
            int col = n0 + wc + j * 16 + lr;
            if (col < N) {
                float bv = bias ? bias[col] : 0.f;
                #pragma unroll
                for (int r = 0; r < 4; ++r) {
                    float v = acc[i][j][r] + bv;
                    if (resid) v += resid[(size_t)(row + r) * N + col];
                    C[(size_t)(row + r) * N + col] = v;
                }
            }
        }
    }
}

// ---------------- f32 tiled GEMM (small shapes: xproj, dt) ----------------
template<int ACT>
__global__ __launch_bounds__(256) void gemm_tiled(
    const float* __restrict__ A, const float* __restrict__ Bm,
    const float* __restrict__ bias, float* __restrict__ C,
    int M, int N, int K, int lda)
{
    __shared__ float As[KT][TS + 4];
    __shared__ float Bs[KT][TS + 4];
    int tid = threadIdx.x;
    int tx = tid & 15, ty = tid >> 4;
    int m0 = blockIdx.y * TS;
    int n0 = blockIdx.x * TS;
    float acc[4][4] = {};

    for (int k0 = 0; k0 < K; k0 += KT) {
        {
            int i = tid >> 2;
            int k4 = (tid & 3) * 4;
            int m = m0 + i;
            float4 v = make_float4(0.f, 0.f, 0.f, 0.f);
            if (m < M) v = *(const float4*)(A + (size_t)m * lda + k0 + k4);
            As[k4 + 0][i] = v.x; As[k4 + 1][i] = v.y;
            As[k4 + 2][i] = v.z; As[k4 + 3][i] = v.w;
        }
        {
            int k = tid >> 4;
            int j4 = (tid & 15) * 4;
            int n = n0 + j4;
            float4 v = make_float4(0.f, 0.f, 0.f, 0.f);
            const float* p = Bm + (size_t)(k0 + k) * N + n;
            if (n + 3 < N) {
                v = *(const float4*)p;
            } else {
                float t0 = (n + 0 < N) ? p[0] : 0.f;
                float t1 = (n + 1 < N) ? p[1] : 0.f;
                float t2 = (n + 2 < N) ? p[2] : 0.f;
                float t3 = (n + 3 < N) ? p[3] : 0.f;
                v = make_float4(t0, t1, t2, t3);
            }
            Bs[k][j4 + 0] = v.x; Bs[k][j4 + 1] = v.y;
            Bs[k][j4 + 2] = v.z; Bs[k][j4 + 3] = v.w;
        }
        __syncthreads();
        #pragma unroll
        for (int k = 0; k < KT; ++k) {
            float a[4], b[4];
            #pragma unroll
            for (int q = 0; q < 4; ++q) a[q] = As[k][ty * 4 + q];
            #pragma unroll
            for (int q = 0; q < 4; ++q) b[q] = Bs[k][tx * 4 + q];
            #pragma unroll
            for (int i = 0; i < 4; ++i)
                #pragma unroll
                for (int j = 0; j < 4; ++j)
                    acc[i][j] = fmaf(a[i], b[j], acc[i][j]);
        }
        __syncthreads();
    }

    #pragma unroll
    for (int i = 0; i < 4; ++i) {
        int m = m0 + ty * 4 + i;
        if (m >= M) continue;
        #pragma unroll
        for (int j = 0; j < 4; ++j) {
            int n = n0 + tx * 4 + j;
            if (n >= N) continue;
            float v = acc[i][j];
            if (bias)  v += bias[n];
            if (ACT == 1) v = fmaxf(v, 0.f) + log1pf(expf(-fabsf(v)));
            C[(size_t)m * N + n] = v;
        }
    }
}

// ---------------- causal depthwise conv1d + SiLU ----------------
__global__ __launch_bounds__(256) void conv_silu_kernel(
    const float* __restrict__ xr, const float* __restrict__ cw,
    const float* __restrict__ cb, float* __restrict__ u)
{
    int d = blockIdx.x * 256 + threadIdx.x;
    int l = blockIdx.y;
    int b = blockIdx.z;
    float acc = cb[d];
    #pragma unroll
    for (int j = 0; j < DC; ++j) {
        int lp = l - (DC - 1) + j;
        if (lp >= 0)
            acc = fmaf(xr[((size_t)(b * LL + lp)) * (2 * DI) + d], cw[d * DC + j], acc);
    }
    float s = acc / (1.f + expf(-acc));
    u[((size_t)(b * LL + l)) * DI + d] = s;
}

// ---------------- chunked selective scan ----------------
// Phase A: per (b, chunk, d, n): P = prod(dA), Q = chunk-local final state
__global__ __launch_bounds__(256) void scan_reduce_kernel(
    const float* __restrict__ delta, const float* __restrict__ u,
    const float* __restrict__ dbc, const float* __restrict__ A_log,
    float* __restrict__ P, float* __restrict__ Q)
{
    int tid = threadIdx.x;
    int n = tid & 15;
    int d = blockIdx.x * 16 + (tid >> 4);
    int c = blockIdx.y;
    int b = blockIdx.z;

    float Av = -expf(A_log[(size_t)d * DS + n]);
    float inv_Aeps = 1.f / (Av + 1e-7f);

    const float* dp = delta + ((size_t)b * LL + c * CH) * DI + d;
    const float* up = u     + ((size_t)b * LL + c * CH) * DI + d;
    const float* bp = dbc   + ((size_t)b * LL + c * CH) * 80 + DR + n;

    float p = 1.f, s = 0.f;
    for (int l = 0; l < CH; ++l) {
        float dlt = dp[(size_t)l * DI];
        float uv  = up[(size_t)l * DI];
        float Bv  = bp[(size_t)l * 80];
        float dA  = expf(dlt * Av);
        float dBu = (dA - 1.f) * inv_Aeps * Bv * uv;
        p *= dA;
        s = fmaf(dA, s, dBu);
    }
    size_t idx = (((size_t)b * NC + c) * DI + d) * DS + n;
    P[idx] = p;
    Q[idx] = s;
}

// Phase B: sequential combine over chunks -> initial state per chunk
__global__ __launch_bounds__(256) void scan_combine_kernel(
    const float* __restrict__ P, const float* __restrict__ Q, float* __restrict__ Sinit)
{
    int t = blockIdx.x * 256 + threadIdx.x;   // over B * DI * DS
    int b = t / (DI * DS);
    int dn = t - b * (DI * DS);
    float s = 0.f;
    for (int c = 0; c < NC; ++c) {
        size_t idx = ((size_t)b * NC + c) * (DI * DS) + dn;
        Sinit[idx] = s;
        s = fmaf(P[idx], s, Q[idx]);
    }
}

// Phase C: re-run chunk from Sinit, produce y = (C.s + u*D) * silu(res)
__global__ __launch_bounds__(256) void scan_apply_kernel(
    const float* __restrict__ delta, const float* __restrict__ u,
    const float* __restrict__ dbc, const float* __restrict__ xr,
    const float* __restrict__ A_log, const float* __restrict__ Dp,
    const float* __restrict__ Sinit, float* __restrict__ y)
{
    int tid = threadIdx.x;
    int n = tid & 15;
    int d = blockIdx.x * 16 + (tid >> 4);
    int c = blockIdx.y;
    int b = blockIdx.z;

    float Av = -expf(A_log[(size_t)d * DS + n]);
    float Dv = Dp[d];
    float inv_Aeps = 1.f / (Av + 1e-7f);

    const float* dp = delta + ((size_t)b * LL + c * CH) * DI + d;
    const float* up = u     + ((size_t)b * LL + c * CH) * DI + d;
    const float* xp = xr    + ((size_t)b * LL + c * CH) * (2 * DI) + DI + d;
    const float* bp = dbc   + ((size_t)b * LL + c * CH) * 80 + DR + n;
    const float* cp = dbc   + ((size_t)b * LL + c * CH) * 80 + DR + DS + n;
    float* yp = y + ((size_t)b * LL + c * CH) * DI + d;

    float s = Sinit[(((size_t)b * NC + c) * DI + d) * DS + n];

    for (int l = 0; l < CH; ++l) {
        float dlt = dp[(size_t)l * DI];
        float uv  = up[(size_t)l * DI];
        float Bv  = bp[(size_t)l * 80];
        float Cv  = cp[(size_t)l * 80];
        float dA  = expf(dlt * Av);
        float dBu = (dA - 1.f) * inv_Aeps * Bv * uv;
        s = fmaf(dA, s, dBu);
        float pv = s * Cv;
        pv += __shfl_xor(pv, 1);
        pv += __shfl_xor(pv, 2);
        pv += __shfl_xor(pv, 4);
        pv += __shfl_xor(pv, 8);
        if (n == 0) {
            float rv = xp[(size_t)l * (2 * DI)];
            float res = rv / (1.f + expf(-rv));
            yp[(size_t)l * DI] = (pv + uv * Dv) * res;
        }
    }
}

// ---------------- RMSNorm ----------------
__global__ __launch_bounds__(256) void rmsnorm_kernel(
    const float* __restrict__ in, const float* __restrict__ w, float* __restrict__ out)
{
    int m = blockIdx.x;
    const float* row = in + (size_t)m * DM;
    float ss = 0.f;
    for (int i = threadIdx.x; i < DM; i += 256) { float v = row[i]; ss = fmaf(v, v, ss); }
    #pragma unroll
    for (int off = 32; off > 0; off >>= 1) ss += __shfl_down(ss, off);
    __shared__ float sred[4];
    __shared__ float sscale;
    int wid = threadIdx.x >> 6;
    if ((threadIdx.x & 63) == 0) sred[wid] = ss;
    __syncthreads();
    if (threadIdx.x == 0) {
        float tot = sred[0] + sred[1] + sred[2] + sred[3];
        sscale = 1.f / sqrtf(tot / (float)DM + 1e-5f);
    }
    __syncthreads();
    float sc = sscale;
    for (int i = threadIdx.x; i < DM; i += 256)
        out[(size_t)m * DM + i] = row[i] * sc * w[i];
}

// ---------------- launch ----------------
extern "C" void kernel_launch(void* const* d_in, const int* in_sizes, int n_in,
                              void* d_out, int out_size, void* d_ws, size_t ws_size,
                              hipStream_t stream)
{
    const int*   ids      = (const int*)  d_in[0];
    const float* emb      = (const float*)d_in[1];
    const float* in_w     = (const float*)d_in[2];
    const float* in_b     = (const float*)d_in[3];
    const float* conv_w   = (const float*)d_in[4];
    const float* conv_b   = (const float*)d_in[5];
    const float* xproj_w  = (const float*)d_in[6];
    const float* dt_w     = (const float*)d_in[7];
    const float* dt_b     = (const float*)d_in[8];
    const float* A_log    = (const float*)d_in[9];
    const float* Dp       = (const float*)d_in[10];
    const float* out_w    = (const float*)d_in[11];
    const float* out_b    = (const float*)d_in[12];
    const float* norm_w   = (const float*)d_in[13];
    const float* normf_w  = (const float*)d_in[14];
    float* out = (float*)d_out;

    char* wsp = (char*)d_ws;
    auto alloc = [&](size_t bytes) {
        char* p = wsp;
        wsp += (bytes + 255) & ~(size_t)255;
        return p;
    };
    float* x     = (float*)alloc((size_t)MM * DM * 4);
    float* xr    = (float*)alloc((size_t)MM * 2 * DI * 4);
    float* u     = (float*)alloc((size_t)MM * DI * 4);
    float* dbc   = (float*)alloc((size_t)MM * 80 * 4);
    float* delta = (float*)alloc((size_t)MM * DI * 4);
    float* yb    = (float*)alloc((size_t)MM * DI * 4);
    float* tmp   = (float*)alloc((size_t)MM * DM * 4);
    float* Pbuf  = (float*)alloc((size_t)BB * NC * DI * DS * 4);
    float* Qbuf  = (float*)alloc((size_t)BB * NC * DI * DS * 4);
    float* Sbuf  = (float*)alloc((size_t)BB * NC * DI * DS * 4);
    unsigned short* a16     = (unsigned short*)alloc((size_t)MM * DI * 2);
    unsigned short* emb16   = (unsigned short*)alloc((size_t)VPAD * DM * 2);
    unsigned short* in_wT   = (unsigned short*)alloc((size_t)NL * 2 * DI * DM * 2);
    unsigned short* out_wT  = (unsigned short*)alloc((size_t)NL * DM * DI * 2);

    emb_convert_kernel<<<VPAD, 256, 0, stream>>>(emb, emb16);
    transpose_bf16_kernel<<<dim3(2 * DI / 32, DM / 32, NL), 256, 0, stream>>>(
        in_w, in_wT, DM, 2 * DI);
    transpose_bf16_kernel<<<dim3(DM / 32, DI / 32, NL), 256, 0, stream>>>(
        out_w, out_wT, DI, DM);

    embed_kernel<<<MM, 256, 0, stream>>>(ids, emb, x);

    for (int layer = 0; layer < NL; ++layer) {
        const float* lb_in  = in_b    + (size_t)layer * 2 * DI;
        const float* lcw    = conv_w  + (size_t)layer * DI * DC;
        const float* lcb    = conv_b  + (size_t)layer * DI;
        const float* lxw    = xproj_w + (size_t)layer * DI * (DR + 2 * DS);
        const float* ldtw   = dt_w    + (size_t)layer * DR * DI;
        const float* ldtb   = dt_b    + (size_t)layer * DI;
        const float* lAlog  = A_log   + (size_t)layer * DI * DS;
        const float* lDp    = Dp      + (size_t)layer * DI;
        const float* lob    = out_b   + (size_t)layer * DM;
        const float* lnw    = norm_w  + (size_t)layer * DM;
        const unsigned short* lw_inT = in_wT  + (size_t)layer * 2 * DI * DM;
        const unsigned short* lw_outT= out_wT + (size_t)layer * DM * DI;

        f32_to_bf16_kernel<<<(MM * DM / 4 + 255) / 256, 256, 0, stream>>>(x, a16, MM * DM / 4);

        gemm_mfma_bt<<<dim3(2 * DI / 128, MM / 128), 256, 0, stream>>>(
            a16, lw_inT, lb_in, nullptr, xr, MM, 2 * DI, DM);

        conv_silu_kernel<<<dim3(DI / 256, LL, BB), 256, 0, stream>>>(xr, lcw, lcb, u);

        gemm_tiled<0><<<dim3((80 + TS - 1) / TS, MM / TS), 256, 0, stream>>>(
            u, lxw, nullptr, dbc, MM, DR + 2 * DS, DI, DI);

        gemm_tiled<1><<<dim3(DI / TS, MM / TS), 256, 0, stream>>>(
            dbc, ldtw, ldtb, delta, MM, DI, DR, DR + 2 * DS);

        // chunked scan
        scan_reduce_kernel<<<dim3(DI / 16, NC, BB), 256, 0, stream>>>(
            delta, u, dbc, lAlog, Pbuf, Qbuf);
        scan_combine_kernel<<<(BB * DI * DS) / 256, 256, 0, stream>>>(
            Pbuf, Qbuf, Sbuf);
        scan_apply_kernel<<<dim3(DI / 16, NC, BB), 256, 0, stream>>>(
            delta, u, dbc, xr, lAlog, lDp, Sbuf, yb);

        f32_to_bf16_kernel<<<(MM * DI / 4 + 255) / 256, 256, 0, stream>>>(yb, a16, MM * DI / 4);

        gemm_mfma_bt<<<dim3(DM / 128, MM / 128), 256, 0, stream>>>(
            a16, lw_outT, lob, x, tmp, MM, DM, DI);

        rmsnorm_kernel<<<MM, 256, 0, stream>>>(tmp, lnw, x);
    }

    rmsnorm_kernel<<<MM, 256, 0, stream>>>(x, normf_w, tmp);

    f32_to_bf16_kernel<<<(MM * DM / 4 + 255) / 256, 256, 0, stream>>>(tmp, a16, MM * DM / 4);

    gemm_mfma_bt<<<dim3(VPAD / 128, MM / 128), 256, 0, stream>>>(
        a16, emb16, nullptr, nullptr, out, MM, VV, DM);
}